// Round 10
// baseline (46.370 us; speedup 1.0000x reference)
//
#include <hip/hip_runtime.h>
#include <math.h>

#define BB 256
#define FF 39
#define EE 16
#define II 741
#define BN_EPS 1e-5f
#define CPW 8            // channels per wave
#define NB 8             // batches per block (main kernel)
#define NCX 24           // channel-blocks: ceil(741/32)
#define NGY (BB / NB)    // 32
#define NROW (BB * FF)   // 9984

typedef float vfloat4 __attribute__((ext_vector_type(4)));
typedef float vfloat2 __attribute__((ext_vector_type(2)));

// Compile-time strict-lower-triangle offsets: v[i] = (r*EE)<<16 | (c*EE),
// row-major pair order matching np.tril_indices(F, -1).
struct OffTab { unsigned int v[II]; };
static constexpr OffTab make_off() {
    OffTab t{};
    int i = 0;
    for (int r = 1; r < FF; ++r)
        for (int c = 0; c < r; ++c) {
            t.v[i] = ((unsigned)(r * EE) << 16) | (unsigned)(c * EE);
            ++i;
        }
    return t;
}
__constant__ OffTab g_off = make_off();

// ws layout (float2 entries, TRANSPOSED f-major/b-minor):
//   Ti[f*BB + b] = (S, Q) of xi row (b,f)   at ws floats [0 .. 2*NROW)
//   Tj[f*BB + b] = (S, Q) of xj row (b,f)   at ws floats [2*NROW .. 4*NROW)
// Transposed so the main kernel's per-wave stats preamble reads coalesced
// 256B segments: T[r*256 + lane + 64m].

__global__ void rowsumT_kernel(const float* __restrict__ xi,
                               const float* __restrict__ xj,
                               float* __restrict__ ws) {
    int t = blockIdx.x * blockDim.x + threadIdx.x;
    if (t >= 2 * NROW) return;
    int tensor = (t >= NROW) ? 1 : 0;
    int row = tensor ? (t - NROW) : t;
    int b = row / FF;            // compiler: magic-mul for const 39
    int f = row - b * FF;
    const float* src = (tensor ? xj : xi) + row * EE;
    float s = 0.f, q = 0.f;
#pragma unroll
    for (int k = 0; k < 4; ++k) {
        vfloat4 v = reinterpret_cast<const vfloat4*>(src)[k];
        s += v.x + v.y + v.z + v.w;
        q += v.x * v.x + v.y * v.y + v.z * v.z + v.w * v.w;
    }
    vfloat2* base = reinterpret_cast<vfloat2*>(ws) + (tensor ? NROW : 0);
    vfloat2 e; e.x = s; e.y = q;
    base[f * BB + b] = e;
}

// out[b,i,e1,e2] = ((xj[b,r,e1]*xi[b,c,e2]) * a[i] + d[i]) * W[e1,e2]
// 4 waves/block; wave owns 8 consecutive channels x 8 batches.
// Per-wave PREAMBLE computes (a,d) for its own 8 channels from the
// transposed (S,Q) tables (coalesced, L2-hot) -> no stats kernel.
#define LOADB(S, V, b)                                                        \
    {                                                                         \
        const float* xib_ = xi + (b) * FF * EE;                               \
        const float* xjb_ = xj + (b) * FF * EE;                               \
        _Pragma("unroll") for (int k = 0; k < CPW; ++k) {                     \
            S[k] = xjb_[joff[k] + e1];                                        \
            V[k] = reinterpret_cast<const vfloat4*>(xib_ + coff[k])[e2q];     \
        }                                                                     \
    }

#define STOREB(S, V, b)                                                       \
    {                                                                         \
        float* outb_ = out + (size_t)(b) * (II * EE * EE)                     \
                       + (size_t)ibase * (EE * EE);                           \
        _Pragma("unroll") for (int k = 0; k < CPW; ++k) {                     \
            vfloat4 o4;                                                       \
            o4.x = (S[k] * V[k].x * a[k] + d[k]) * w4.x;                      \
            o4.y = (S[k] * V[k].y * a[k] + d[k]) * w4.y;                      \
            o4.z = (S[k] * V[k].z * a[k] + d[k]) * w4.z;                      \
            o4.w = (S[k] * V[k].w * a[k] + d[k]) * w4.w;                      \
            reinterpret_cast<vfloat4*>(outb_ + k * (EE * EE))[l] = o4;        \
        }                                                                     \
    }

__global__ __launch_bounds__(256) void
cross_bn_kernel(const float* __restrict__ xi,
                const float* __restrict__ xj,
                const float* __restrict__ W,
                const float* __restrict__ gamma,
                const float* __restrict__ beta,
                const float* __restrict__ ws,
                float* __restrict__ out) {
    const vfloat2* Ti = reinterpret_cast<const vfloat2*>(ws);
    const vfloat2* Tj = Ti + NROW;

    int t = threadIdx.x;
    int l = t & 63;        // lane in wave
    int e1 = l >> 2;       // 0..15
    int e2q = l & 3;       // float4 index along e2
    int wv = t >> 6;       // wave id 0..3

    vfloat4 w4 = reinterpret_cast<const vfloat4*>(W)[e1 * 4 + e2q];

    int ibase = __builtin_amdgcn_readfirstlane(blockIdx.x * (4 * CPW) + wv * CPW);
    int b0 = blockIdx.y * NB;
    int nval = II - ibase;                  // valid channels this wave
    if (nval <= 0) return;                  // wv>=1 at cx==23
    if (nval > CPW) nval = CPW;

    // ---------------- preamble: (a,d) for this wave's channels --------------
    int joff[CPW], coff[CPW];
    float a[CPW], d[CPW];
    const float invN = 1.0f / (float)(BB * EE * EE);  // 1/65536
#pragma unroll
    for (int k = 0; k < CPW; ++k) {
        if (k < nval) {  // wave-uniform predicate
            unsigned o = g_off.v[ibase + k];
            joff[k] = (int)(o >> 16);       // r*16
            coff[k] = (int)(o & 0xffffu);   // c*16
            int rb = joff[k] * (BB / EE);   // r*256
            int cb = coff[k] * (BB / EE);   // c*256
            float sS = 0.f, sQ = 0.f;
#pragma unroll
            for (int m = 0; m < 4; ++m) {
                int b = l + 64 * m;
                vfloat2 pj = Tj[rb + b];
                vfloat2 pi = Ti[cb + b];
                sS += pj.x * pi.x;
                sQ += pj.y * pi.y;
            }
#pragma unroll
            for (int off = 32; off > 0; off >>= 1) {
                sS += __shfl_xor(sS, off);
                sQ += __shfl_xor(sQ, off);
            }
            float mean = sS * invN;
            float var = sQ * invN - mean * mean;
            float inv_std = 1.0f / sqrtf(var + BN_EPS);
            a[k] = gamma[ibase + k] * inv_std;
            d[k] = beta[ibase + k] - mean * a[k];
        }
    }

    // ---------------- streaming store phase ----------------
    if (nval == CPW) {
        float sA[CPW], sB[CPW];
        vfloat4 vA[CPW], vB[CPW];
        // prologue: 2 batches in flight
        LOADB(sA, vA, b0 + 0)
        LOADB(sB, vB, b0 + 1)
        // steady state: store(b), then load(b+2) into the freed buffer
        STOREB(sA, vA, b0 + 0)  LOADB(sA, vA, b0 + 2)
        STOREB(sB, vB, b0 + 1)  LOADB(sB, vB, b0 + 3)
        STOREB(sA, vA, b0 + 2)  LOADB(sA, vA, b0 + 4)
        STOREB(sB, vB, b0 + 3)  LOADB(sB, vB, b0 + 5)
        STOREB(sA, vA, b0 + 4)  LOADB(sA, vA, b0 + 6)
        STOREB(sB, vB, b0 + 5)  LOADB(sB, vB, b0 + 7)
        STOREB(sA, vA, b0 + 6)
        STOREB(sB, vB, b0 + 7)
    } else {
        // tail (cx==23, wv==0: channels 736..740)
#pragma unroll
        for (int bb = 0; bb < NB; ++bb) {
            int b = b0 + bb;
            const float* xib = xi + b * FF * EE;
            const float* xjb = xj + b * FF * EE;
            float* outb = out + (size_t)b * (II * EE * EE);
            for (int k = 0; k < nval; ++k) {
                int i = ibase + k;
                float xjs = xjb[joff[k] + e1];
                vfloat4 xi4 = reinterpret_cast<const vfloat4*>(xib + coff[k])[e2q];
                vfloat4 o4;
                o4.x = (xjs * xi4.x * a[k] + d[k]) * w4.x;
                o4.y = (xjs * xi4.y * a[k] + d[k]) * w4.y;
                o4.z = (xjs * xi4.z * a[k] + d[k]) * w4.z;
                o4.w = (xjs * xi4.w * a[k] + d[k]) * w4.w;
                reinterpret_cast<vfloat4*>(outb + (size_t)i * (EE * EE))[l] = o4;
            }
        }
    }
}

extern "C" void kernel_launch(void* const* d_in, const int* in_sizes, int n_in,
                              void* d_out, int out_size, void* d_ws, size_t ws_size,
                              hipStream_t stream) {
    const float* xi = (const float*)d_in[0];
    const float* xj = (const float*)d_in[1];
    const float* W = (const float*)d_in[2];
    const float* gamma = (const float*)d_in[3];
    const float* beta = (const float*)d_in[4];
    float* out = (float*)d_out;
    float* ws = (float*)d_ws;

    rowsumT_kernel<<<dim3((2 * NROW + 255) / 256), 256, 0, stream>>>(xi, xj, ws);
    cross_bn_kernel<<<dim3(NCX, NGY), 256, 0, stream>>>(xi, xj, W, gamma, beta, ws, out);
}

// Round 11
// 44.398 us; speedup vs baseline: 1.0444x; 1.0444x over previous
//
#include <hip/hip_runtime.h>
#include <math.h>

#define BB 256
#define FF 39
#define EE 16
#define II 741
#define BN_EPS 1e-5f
#define CPW 8            // channels per wave
#define NB 8             // batches per block (main kernel)
#define NCX 24           // channel-blocks: ceil(741/32)
#define NGY (BB / NB)    // 32
#define NROW (BB * FF)   // 9984
#define BFE (FF * EE)    // 624 floats per (batch, tensor)

typedef float vfloat4 __attribute__((ext_vector_type(4)));
typedef float vfloat2 __attribute__((ext_vector_type(2)));

// Compile-time strict-lower-triangle offsets: v[i] = (r*EE)<<16 | (c*EE),
// row-major pair order matching np.tril_indices(F, -1).
struct OffTab { unsigned int v[II]; };
static constexpr OffTab make_off() {
    OffTab t{};
    int i = 0;
    for (int r = 1; r < FF; ++r)
        for (int c = 0; c < r; ++c) {
            t.v[i] = ((unsigned)(r * EE) << 16) | (unsigned)(c * EE);
            ++i;
        }
    return t;
}
__constant__ OffTab g_off = make_off();

// ws layout (floats): T2[I] = (a, d) per channel. ~6 KB.

// One wave per channel (r6-proven). Lanes split the batch dim;
// butterfly-reduce; lane 0 folds BN stats into affine (a,d).
__global__ __launch_bounds__(256) void
stats_kernel(const float* __restrict__ xi,
             const float* __restrict__ xj,
             const float* __restrict__ gamma,
             const float* __restrict__ beta,
             float* __restrict__ ws) {
    int wid = (blockIdx.x * blockDim.x + threadIdx.x) >> 6;  // global wave = channel
    int lane = threadIdx.x & 63;
    if (wid >= II) return;
    int i = wid;
    unsigned o = g_off.v[i];
    int joff = (int)(o >> 16);
    int coff = (int)(o & 0xffffu);

    float sumS = 0.f, sumQ = 0.f;
#pragma unroll
    for (int b = lane; b < BB; b += 64) {
        const vfloat4* xjr = reinterpret_cast<const vfloat4*>(xj + b * BFE + joff);
        const vfloat4* xic = reinterpret_cast<const vfloat4*>(xi + b * BFE + coff);
        float sj = 0.f, qj = 0.f, si = 0.f, qi = 0.f;
#pragma unroll
        for (int k = 0; k < 4; ++k) {
            vfloat4 vj = xjr[k];
            vfloat4 vi = xic[k];
            sj += vj.x + vj.y + vj.z + vj.w;
            qj += vj.x * vj.x + vj.y * vj.y + vj.z * vj.z + vj.w * vj.w;
            si += vi.x + vi.y + vi.z + vi.w;
            qi += vi.x * vi.x + vi.y * vi.y + vi.z * vi.z + vi.w * vi.w;
        }
        sumS += sj * si;
        sumQ += qj * qi;
    }
#pragma unroll
    for (int off = 32; off > 0; off >>= 1) {
        sumS += __shfl_xor(sumS, off);
        sumQ += __shfl_xor(sumQ, off);
    }
    if (lane == 0) {
        const float invN = 1.0f / (float)(BB * EE * EE);  // 1/65536
        float mean = sumS * invN;
        float ex2 = sumQ * invN;
        float var = ex2 - mean * mean;
        float inv_std = 1.0f / sqrtf(var + BN_EPS);
        float a = gamma[i] * inv_std;
        float d = beta[i] - mean * a;
        vfloat2 e;
        e.x = a; e.y = d;
        reinterpret_cast<vfloat2*>(ws)[i] = e;
    }
}

// out[b,i,e1,e2] = ((xj[b,r,e1]*xi[b,c,e2]) * a[i] + d[i]) * W[e1,e2]
// Block: 4 waves; wave owns 8 consecutive channels x 8 batches.
// Phase 1: stage this block's 8 batches of xi+xj into LDS (39 KB, coalesced).
// Phase 2: pure-write streaming — operands from LDS only, so HBM sees an
// uncontaminated store stream (no read/write turnaround).
__global__ __launch_bounds__(256) void
cross_bn_kernel(const float* __restrict__ xi,
                const float* __restrict__ xj,
                const float* __restrict__ W,
                const float* __restrict__ ws,
                float* __restrict__ out) {
    __shared__ float xi_lds[NB * BFE];  // 4992 floats
    __shared__ float xj_lds[NB * BFE];

    const vfloat2* T2 = reinterpret_cast<const vfloat2*>(ws);

    int t = threadIdx.x;
    int b0 = blockIdx.y * NB;

    // ---------------- Phase 1: global -> LDS staging ----------------
    {
        const vfloat4* gxi = reinterpret_cast<const vfloat4*>(xi + b0 * BFE);
        const vfloat4* gxj = reinterpret_cast<const vfloat4*>(xj + b0 * BFE);
        vfloat4* sxi = reinterpret_cast<vfloat4*>(xi_lds);
        vfloat4* sxj = reinterpret_cast<vfloat4*>(xj_lds);
        const int NCHUNK = NB * BFE / 4;  // 1248
        for (int idx = t; idx < NCHUNK; idx += 256) sxi[idx] = gxi[idx];
        for (int idx = t; idx < NCHUNK; idx += 256) sxj[idx] = gxj[idx];
    }
    __syncthreads();

    // ---------------- Phase 2: streaming stores ----------------
    int l = t & 63;        // lane in wave
    int e1 = l >> 2;       // 0..15
    int e2q = l & 3;       // float4 index along e2
    int wv = t >> 6;       // wave id 0..3

    vfloat4 w4 = reinterpret_cast<const vfloat4*>(W)[e1 * 4 + e2q];

    int ibase = __builtin_amdgcn_readfirstlane(blockIdx.x * (4 * CPW) + wv * CPW);
    int nval = II - ibase;                  // valid channels this wave
    if (nval > CPW) nval = CPW;

    if (nval == CPW) {
        // per-channel scalars (wave-uniform -> scalar loads)
        int joff[CPW], coff[CPW];
        float a[CPW], d[CPW];
#pragma unroll
        for (int k = 0; k < CPW; ++k) {
            unsigned o = g_off.v[ibase + k];
            joff[k] = (int)(o >> 16);
            coff[k] = (int)(o & 0xffffu);
            vfloat2 ad = T2[ibase + k];
            a[k] = ad.x; d[k] = ad.y;
        }
#pragma unroll
        for (int bb = 0; bb < NB; ++bb) {
            const float* xib = xi_lds + bb * BFE;
            const float* xjb = xj_lds + bb * BFE;
            float* outb = out + (size_t)(b0 + bb) * (II * EE * EE)
                          + (size_t)ibase * (EE * EE);
#pragma unroll
            for (int k = 0; k < CPW; ++k) {
                float xjs = xjb[joff[k] + e1];
                vfloat4 xi4 = reinterpret_cast<const vfloat4*>(xib + coff[k])[e2q];
                vfloat4 o4;
                o4.x = (xjs * xi4.x * a[k] + d[k]) * w4.x;
                o4.y = (xjs * xi4.y * a[k] + d[k]) * w4.y;
                o4.z = (xjs * xi4.z * a[k] + d[k]) * w4.z;
                o4.w = (xjs * xi4.w * a[k] + d[k]) * w4.w;
                reinterpret_cast<vfloat4*>(outb + k * (EE * EE))[l] = o4;
            }
        }
    } else if (nval > 0) {
        // tail (cx==23, wv==0: channels 736..740)
#pragma unroll
        for (int bb = 0; bb < NB; ++bb) {
            const float* xib = xi_lds + bb * BFE;
            const float* xjb = xj_lds + bb * BFE;
            float* outb = out + (size_t)(b0 + bb) * (II * EE * EE);
            for (int k = 0; k < nval; ++k) {
                int i = ibase + k;
                unsigned o = g_off.v[i];
                int joff = (int)(o >> 16);
                int coff = (int)(o & 0xffffu);
                vfloat2 ad = T2[i];
                float xjs = xjb[joff + e1];
                vfloat4 xi4 = reinterpret_cast<const vfloat4*>(xib + coff)[e2q];
                vfloat4 o4;
                o4.x = (xjs * xi4.x * ad.x + ad.y) * w4.x;
                o4.y = (xjs * xi4.y * ad.x + ad.y) * w4.y;
                o4.z = (xjs * xi4.z * ad.x + ad.y) * w4.z;
                o4.w = (xjs * xi4.w * ad.x + ad.y) * w4.w;
                reinterpret_cast<vfloat4*>(outb + (size_t)i * (EE * EE))[l] = o4;
            }
        }
    }
}

extern "C" void kernel_launch(void* const* d_in, const int* in_sizes, int n_in,
                              void* d_out, int out_size, void* d_ws, size_t ws_size,
                              hipStream_t stream) {
    const float* xi = (const float*)d_in[0];
    const float* xj = (const float*)d_in[1];
    const float* W = (const float*)d_in[2];
    const float* gamma = (const float*)d_in[3];
    const float* beta = (const float*)d_in[4];
    float* out = (float*)d_out;
    float* ws = (float*)d_ws;

    stats_kernel<<<dim3((II * 64 + 255) / 256), 256, 0, stream>>>(xi, xj, gamma, beta, ws);
    cross_bn_kernel<<<dim3(NCX, NGY), 256, 0, stream>>>(xi, xj, W, ws, out);
}